// Round 10
// baseline (192.487 us; speedup 1.0000x reference)
//
#include <hip/hip_runtime.h>
#include <math.h>

#define NTT 365
#define NSS 300
#define NROWS (NTT*NSS)   // 109500
#define TPAD2 416         // PT pad
#define NVROWS 384        // NV time rows (t + 16 lookahead < 384)

using bf16x8 = __attribute__((ext_vector_type(8))) short;
using f32x4  = __attribute__((ext_vector_type(4))) float;

__device__ __forceinline__ float sigf(float v) { return 1.0f / (1.0f + __expf(-v)); }

__device__ __forceinline__ float tanhfast(float x) {
    float e = __expf(2.0f * x);
    return 1.0f - 2.0f * __builtin_amdgcn_rcpf(1.0f + e);
}

__device__ __forceinline__ unsigned short f2bf(float f) {
    unsigned u = __builtin_bit_cast(unsigned, f);
    u += 0x7FFFu + ((u >> 16) & 1u);
    return (unsigned short)(u >> 16);
}

// ---------------- K0: swizzle fcT weights to fragment-major bf16 ----------------
__global__ __launch_bounds__(256) void k_prep(const float* __restrict__ w1,
                                              const float* __restrict__ w2,
                                              unsigned short* __restrict__ w1s,
                                              unsigned short* __restrict__ w2s)
{
    int G = blockIdx.x * 256 + threadIdx.x;
    if (G < 2048) {
        int lane = G & 63, ks = (G >> 6) & 1, tile = G >> 7;
        int o = tile * 16 + (lane & 15);
        int kb = ks * 32 + (lane >> 4) * 8;
        unsigned short tmp[8];
#pragma unroll
        for (int e = 0; e < 8; ++e) {
            int k = kb + e;
            tmp[e] = (k < 38) ? f2bf(w1[o * 38 + k]) : (unsigned short)0;
        }
        *(bf16x8*)(w1s + (size_t)G * 8) = *(bf16x8*)tmp;
    } else if (G < 2048 + 12288) {
        int G2 = G - 2048;
        int lane = G2 & 63, ks = (G2 >> 6) & 7, tile = G2 >> 9;
        int o = tile * 16 + (lane & 15);
        int kb = ks * 32 + (lane >> 4) * 8;
        unsigned short tmp[8];
#pragma unroll
        for (int e = 0; e < 8; ++e) tmp[e] = f2bf(w2[o * 256 + kb + e]);
        *(bf16x8*)(w2s + (size_t)G2 * 8) = *(bf16x8*)tmp;
    }
}

// ---------------- K1: per-site MLPs, output-sliced grid (30 x 8) ----------------
__global__ __launch_bounds__(256) void k_site(
    const float* __restrict__ xc,
    const float* __restrict__ wW1, const float* __restrict__ bW1,
    const float* __restrict__ wW2, const float* __restrict__ bW2,
    const float* __restrict__ wR1, const float* __restrict__ bR1,
    const float* __restrict__ wR2, const float* __restrict__ bR2,
    float* __restrict__ wsite, float* __restrict__ rsite)
{
    __shared__ float xcb[10][32];
    __shared__ float hW[10][256];
    __shared__ float hR[10][256];
    int tid = threadIdx.x;
    int s0 = blockIdx.x * 10;
    int os = blockIdx.y;              // 0..7 output slice
    for (int i = tid; i < 10 * 32; i += 256) xcb[i / 32][i % 32] = xc[s0 * 32 + i];
    __syncthreads();
    {
        int j = tid;
        float aW[10], aR[10];
#pragma unroll
        for (int r = 0; r < 10; ++r) { aW[r] = bW1[j]; aR[r] = bR1[j]; }
        for (int k = 0; k < 32; ++k) {
            float wv = wW1[j * 32 + k], rv = wR1[j * 32 + k];
#pragma unroll
            for (int r = 0; r < 10; ++r) { float xv = xcb[r][k]; aW[r] += xv * wv; aR[r] += xv * rv; }
        }
#pragma unroll
        for (int r = 0; r < 10; ++r) { hW[r][j] = tanhfast(aW[r]); hR[r][j] = tanhfast(aR[r]); }
    }
    __syncthreads();
    if (tid < 240) {
        int o_lin = os * 240 + tid;   // 0..1919
        float acc[10];
        if (o_lin < 896) {
            int o = o_lin;
#pragma unroll
            for (int r = 0; r < 10; ++r) acc[r] = bW2[o];
            for (int k = 0; k < 256; ++k) {
                float wv = wW2[o * 256 + k];
#pragma unroll
                for (int r = 0; r < 10; ++r) acc[r] += hW[r][k] * wv;
            }
#pragma unroll
            for (int r = 0; r < 10; ++r) wsite[(s0 + r) * 896 + o] = acc[r];
        } else {
            int o = o_lin - 896;      // 0..1023
#pragma unroll
            for (int r = 0; r < 10; ++r) acc[r] = bR2[o];
            for (int k = 0; k < 256; ++k) {
                float wv = wR2[o * 256 + k];
#pragma unroll
                for (int r = 0; r < 10; ++r) acc[r] += hR[r][k] * wv;
            }
#pragma unroll
            for (int r = 0; r < 10; ++r) rsite[(s0 + r) * 1024 + o] = acc[r];
        }
    }
}

// ---------------- K1b: softmax of ga over h per site ----------------
__global__ __launch_bounds__(128) void k_softmax_ga(const float* __restrict__ wsite,
                                                    float* __restrict__ ga)
{
    int s = blockIdx.x, tid = threadIdx.x;
    __shared__ float red[2];
    float v = wsite[s * 896 + 6 * 128 + tid];
    float m = v;
#pragma unroll
    for (int off = 32; off >= 1; off >>= 1) m = fmaxf(m, __shfl_xor(m, off));
    if ((tid & 63) == 0) red[tid >> 6] = m;
    __syncthreads();
    m = fmaxf(red[0], red[1]);
    __syncthreads();
    float e = __expf(v - m);
    float ssum = e;
#pragma unroll
    for (int off = 32; off >= 1; off >>= 1) ssum += __shfl_xor(ssum, off);
    if ((tid & 63) == 0) red[tid >> 6] = ssum;
    __syncthreads();
    ssum = red[0] + red[1];
    ga[s * 128 + tid] = e / ssum;
}

// ---------------- K1c: precompute ct gate params per (s,h) ----------------
__global__ __launch_bounds__(128) void k_ct(const float* __restrict__ xc,
                                            const float* __restrict__ ctw,
                                            const float* __restrict__ ctb,
                                            float* __restrict__ ctp8,
                                            float* __restrict__ ctpb)
{
    __shared__ float xcs[32];
    int s = blockIdx.x, h = threadIdx.x;
    if (h < 32) xcs[h] = xc[s * 32 + h];
    __syncthreads();
    const float L2E = 1.4426950408889634f;
    const float LG01 = -3.3219280948873623f;   // log2(0.1): folds /10 into cp
    float out[8];
    float cgb = 0.0f;
#pragma unroll
    for (int g = 0; g < 3; ++g) {
        const float* wr = ctw + (g * 128 + h) * 34;
        float base = ctb[g * 128 + h];
        for (int k = 0; k < 32; ++k) base += wr[2 + k] * xcs[k];
        float w0 = wr[0] * L2E, w1 = wr[1] * L2E;
        float bb = base * L2E + ((g == 0) ? LG01 : 0.0f);
        if (g == 0) { out[0] = w0; out[1] = w1; out[2] = bb; }
        else if (g == 1) { out[3] = w0; out[4] = w1; out[5] = bb; }
        else { out[6] = w0; out[7] = w1; cgb = bb; }
    }
    float4* dst = (float4*)(ctp8 + ((size_t)s * 128 + h) * 8);
    dst[0] = make_float4(out[0], out[1], out[2], out[3]);
    dst[1] = make_float4(out[4], out[5], out[6], out[7]);
    ctpb[(size_t)s * 128 + h] = cgb;
}

// ---------------- K2: fcT MLP via bf16 MFMA -> PTt[s][t], NVu[t][s][h] ----------------
__global__ __launch_bounds__(512, 4) void k_fcT(
    const float* __restrict__ x, const float* __restrict__ xc,
    const unsigned short* __restrict__ w1s, const float* __restrict__ b1,
    const unsigned short* __restrict__ w2s, const float* __restrict__ b2,
    float4* __restrict__ PTt, unsigned* __restrict__ NVu)
{
    __shared__ unsigned short A1[64][72];
    __shared__ unsigned short hb[64][264];
    __shared__ float2 pfE[64];           // {P*(1-vf), 2*E}
    int tid = threadIdx.x;
    int row0 = blockIdx.x * 64;

    for (int idx = tid; idx < 64 * 64; idx += 512) {
        int r = idx >> 6, c = idx & 63;
        int g = row0 + r;
        float val = 0.0f;
        if (g < NROWS) {
            if (c < 6) val = x[g * 6 + c];
            else if (c < 38) { int s = g % NSS; val = xc[s * 32 + (c - 6)]; }
        }
        A1[r][c] = f2bf(val);
    }
    if (tid < 64) {
        int r = tid, g = row0 + r;
        float P = 0, E = 0, T1 = 0, T2 = 0;
        if (g < NROWS) { P = x[g * 6]; E = x[g * 6 + 1]; T1 = x[g * 6 + 2]; T2 = x[g * 6 + 3]; }
        float den = T2 - T1;
        float dg = (den == 0.0f) ? 1.0f : den;
        float ratio = fminf(fmaxf((T1 + T2) / dg, -1.0f), 1.0f);
        float vf = acosf(ratio) * (1.0f / 3.1415f);
        vf = (T1 >= 0.0f) ? 0.0f : ((T2 <= 0.0f) ? 1.0f : vf);
        pfE[r] = make_float2(P * (1.0f - vf), 2.0f * E);
        if (g < NROWS) {
            int tg = g / NSS, sg = g - tg * NSS;
            PTt[(size_t)sg * TPAD2 + tg] = make_float4(P * vf, T1, T2, vf);
        }
    }
    __syncthreads();

    int lane = tid & 63, wv = tid >> 6;
    int r16 = lane & 15;
    int kg = (lane >> 4) * 8;     // k offset within 32-chunk
    int rq = (lane >> 4) * 4;     // row offset of C frag

    // ---- layer 1: [64 x 64(Kpad)] @ [256 x 64]^T -> hidden (bf16) ----
    {
        int mt = wv & 3, nb = (wv >> 2) * 8;
        f32x4 acc[8];
#pragma unroll
        for (int i = 0; i < 8; ++i) acc[i] = (f32x4){0.f, 0.f, 0.f, 0.f};
#pragma unroll
        for (int ks = 0; ks < 2; ++ks) {
            bf16x8 a = *(const bf16x8*)&A1[mt * 16 + r16][ks * 32 + kg];
#pragma unroll
            for (int i = 0; i < 8; ++i) {
                bf16x8 b = *(const bf16x8*)(w1s + ((size_t)(((nb + i) * 2 + ks) * 64 + lane) << 3));
                acc[i] = __builtin_amdgcn_mfma_f32_16x16x32_bf16(a, b, acc[i], 0, 0, 0);
            }
        }
#pragma unroll
        for (int i = 0; i < 8; ++i) {
            int col = (nb + i) * 16 + r16;
            float bias = b1[col];
#pragma unroll
            for (int j = 0; j < 4; ++j) {
                int row = mt * 16 + rq + j;
                hb[row][col] = f2bf(tanhfast(acc[i][j] + bias));
            }
        }
    }
    __syncthreads();

    // ---- layer 2: [64 x 256] @ [384 x 256]^T, wave w -> col tiles {w, w+8, w+16} ----
    {
        int t0 = wv, t1 = wv + 8, t2 = wv + 16;
        f32x4 acc[4][3];
#pragma unroll
        for (int m = 0; m < 4; ++m)
#pragma unroll
            for (int c = 0; c < 3; ++c) acc[m][c] = (f32x4){0.f, 0.f, 0.f, 0.f};
#pragma unroll
        for (int ks = 0; ks < 8; ++ks) {
            bf16x8 b0 = *(const bf16x8*)(w2s + ((size_t)((t0 * 8 + ks) * 64 + lane) << 3));
            bf16x8 b1v = *(const bf16x8*)(w2s + ((size_t)((t1 * 8 + ks) * 64 + lane) << 3));
            bf16x8 b2v = *(const bf16x8*)(w2s + ((size_t)((t2 * 8 + ks) * 64 + lane) << 3));
#pragma unroll
            for (int m = 0; m < 4; ++m) {
                bf16x8 a = *(const bf16x8*)&hb[m * 16 + r16][ks * 32 + kg];
                acc[m][0] = __builtin_amdgcn_mfma_f32_16x16x32_bf16(a, b0, acc[m][0], 0, 0, 0);
                acc[m][1] = __builtin_amdgcn_mfma_f32_16x16x32_bf16(a, b1v, acc[m][1], 0, 0, 0);
                acc[m][2] = __builtin_amdgcn_mfma_f32_16x16x32_bf16(a, b2v, acc[m][2], 0, 0, 0);
            }
        }
        int hcol = wv * 16 + r16;     // h in [0,128)
        float bias0 = b2[hcol], bias1 = b2[128 + hcol], bias2 = b2[256 + hcol];
#pragma unroll
        for (int m = 0; m < 4; ++m) {
            float2 pf[4];
#pragma unroll
            for (int j = 0; j < 4; ++j) pf[j] = pfE[m * 16 + rq + j];
#pragma unroll
            for (int j = 0; j < 4; ++j) {
                int r = m * 16 + rq + j;
                int g = row0 + r;
                if (g < NROWS) {
                    float vi = fminf(fmaxf((acc[m][0][j] + bias0) * (1.0f / 3.0f) + 0.5f, 0.0f), 1.0f);
                    float pl = pf[j].x * vi;
                    float ev = pf[j].y * fmaxf(acc[m][1][j] + bias1, 0.0f);
                    float vmv = __expf(acc[m][2][j] + bias2);
                    unsigned pk = (unsigned)f2bf(pl - ev) | ((unsigned)f2bf(vmv) << 16);
                    NVu[(size_t)g * 128 + hcol] = pk;   // [t][s][h] (g = t*NSS+s)
                }
            }
        }
    }
}

// ---------------- K3: merged-halves role-split scan, barrier-pinned pipeline ----------------
template<int ISC>
__device__ __forceinline__ void scan_body(
    int lane, int s,
    const float* __restrict__ wrow, const float* __restrict__ rsite,
    const float* __restrict__ gaw, const float* __restrict__ ctp8,
    const float* __restrict__ ctpb,
    const unsigned* __restrict__ NVu, const float4* ptlds, float (*red)[68],
    float* __restrict__ outp)
{
    // per-chain params, chains c=0,1 -> h = 2*lane + c
    float kp[2], ksv[2], kgv[2], gpv[2], gpc[2], gLv[2], kpgl[2], qbv[2];
    {
        float2 v0 = *(const float2*)(wrow + 0 * 128 + 2 * lane);
        float2 v1 = *(const float2*)(wrow + 1 * 128 + 2 * lane);
        float2 v2 = *(const float2*)(wrow + 2 * 128 + 2 * lane);
        float2 v3 = *(const float2*)(wrow + 3 * 128 + 2 * lane);
        float2 v4 = *(const float2*)(wrow + 4 * 128 + 2 * lane);
        float2 v5 = *(const float2*)(wrow + 5 * 128 + 2 * lane);
        kp[0] = sigf(v0.x); kp[1] = sigf(v0.y);
        ksv[0] = sigf(v1.x); ksv[1] = sigf(v1.y);
        kgv[0] = sigf(v2.x); kgv[1] = sigf(v2.y);
        gpv[0] = sigf(v3.x); gpv[1] = sigf(v3.y);
        gpc[0] = 1.0f - gpv[0]; gpc[1] = 1.0f - gpv[1];
        gLv[0] = __expf(v4.x) * 2.0f; gLv[1] = __expf(v4.y) * 2.0f;
        kpgl[0] = kp[0] * gLv[0]; kpgl[1] = kp[1] * gLv[1];
        qbv[0] = fmaxf(v5.x, 0.0f); qbv[1] = fmaxf(v5.y, 0.0f);
    }
    float2 gav = *(const float2*)(gaw + s * 128 + 2 * lane);
    float r[2][8];
#pragma unroll
    for (int c = 0; c < 2; ++c) {
        float ga = (c == 0) ? gav.x : gav.y;
        float4 ra = *(const float4*)(rsite + s * 1024 + (2 * lane + c) * 8);
        float4 rb = *(const float4*)(rsite + s * 1024 + (2 * lane + c) * 8 + 4);
        r[c][0] = fmaxf(ra.x, 0.f) * ga; r[c][1] = fmaxf(ra.y, 0.f) * ga;
        r[c][2] = fmaxf(ra.z, 0.f) * ga; r[c][3] = fmaxf(ra.w, 0.f) * ga;
        r[c][4] = fmaxf(rb.x, 0.f) * ga; r[c][5] = fmaxf(rb.y, 0.f) * ga;
        r[c][6] = fmaxf(rb.z, 0.f) * ga; r[c][7] = fmaxf(rb.w, 0.f) * ga;
    }
    float ct[2][9];
    if (ISC) {
#pragma unroll
        for (int c = 0; c < 2; ++c) {
            const float4* cp4 = (const float4*)(ctp8 + ((size_t)s * 128 + 2 * lane + c) * 8);
            float4 c0 = cp4[0], c1 = cp4[1];
            ct[c][0] = c0.x; ct[c][1] = c0.y; ct[c][2] = c0.z;
            ct[c][3] = c0.w; ct[c][4] = c1.x; ct[c][5] = c1.y;
            ct[c][6] = c1.z; ct[c][7] = c1.w;
            ct[c][8] = ctpb[(size_t)s * 128 + 2 * lane + c];
        }
    }

    float Sf[2] = {0.f, 0.f}, Ss[2] = {0.f, 0.f}, Sg[2] = {0.f, 0.f};
    float a0 = 0, a1 = 0, a2 = 0, a3 = 0, a4 = 0, a5 = 0, a6 = 0, a7 = 0;

    const unsigned* nvrow = NVu + (size_t)s * 128 + 2 * lane;
#define NVLD(t) (*(const uint2*)(nvrow + (size_t)(t) * (NSS * 128)))

    uint2 A[8], B[8];
#pragma unroll
    for (int i = 0; i < 8; ++i) A[i] = NVLD(i);
#pragma unroll
    for (int i = 0; i < 8; ++i) B[i] = NVLD(8 + i);
    float4 pt[4];
#pragma unroll
    for (int i = 0; i < 4; ++i) pt[i] = ptlds[i];

    auto STEP = [&](int t, uint2 nv) {
        int ps = t & 3;
        float psv = pt[ps].x, T1 = pt[ps].y, T2 = pt[ps].z;
        pt[ps] = ptlds[t + 4];
        unsigned nvw[2] = {nv.x, nv.y};
        float val[2];
#pragma unroll
        for (int c = 0; c < 2; ++c) {
            float net = __builtin_bit_cast(float, nvw[c] << 16);
            float vm  = __builtin_bit_cast(float, nvw[c] & 0xFFFF0000u);
            float t1v = Sf[c] + psv;
            float qf = fminf(t1v, vm);
            Sf[c] = fmaxf(t1v - vm, 0.0f);
            float H = fmaxf(Ss[c] + qf + net, 0.0f);
            float qp = fmaxf(kp[c] * H - kpgl[c], 0.0f);
            float qs = ksv[c] * fminf(H, gLv[c]);
            Ss[c] = H - qp - qs;
            float qso = qs * gpc[c];
            float qsg = qs * gpv[c];
            float tg2 = Sg[c] + qsg;
            float qg = kgv[c] * tg2 + qbv[c];
            Sg[c] = tg2 - qg;
            if (ISC) {
                float cp = exp2f(ct[c][0] * T1 + ct[c][1] * T2 + ct[c][2]);
                float cs = exp2f(ct[c][3] * T1 + ct[c][4] * T2 + ct[c][5]);
                float cg = exp2f(ct[c][6] * T1 + ct[c][7] * T2 + ct[c][8]);
                val[c] = qp * cp + qso * cs + qg * cg;
            } else {
                val[c] = qp + qso + qg;
            }
        }
        a0 += val[0] * r[0][0]; a0 += val[1] * r[1][0];
        a1 += val[0] * r[0][1]; a1 += val[1] * r[1][1];
        a2 += val[0] * r[0][2]; a2 += val[1] * r[1][2];
        a3 += val[0] * r[0][3]; a3 += val[1] * r[1][3];
        a4 += val[0] * r[0][4]; a4 += val[1] * r[1][4];
        a5 += val[0] * r[0][5]; a5 += val[1] * r[1][5];
        a6 += val[0] * r[0][6]; a6 += val[1] * r[1][6];
        a7 += val[0] * r[0][7]; a7 += val[1] * r[1][7];
        red[t & 15][lane] = a0;
        a0 = a1; a1 = a2; a2 = a3; a3 = a4; a4 = a5; a5 = a6; a6 = a7; a7 = 0.0f;
    };

    auto GROUP = [&](int tb, uint2 (&BUF)[8]) {
#pragma unroll
        for (int u = 0; u < 8; ++u) {
            int t = tb + u;
            uint2 cur = BUF[u];
            BUF[u] = NVLD(t + 16);     // issue 16 ahead, pinned above the barrier
            STEP(t, cur);
        }
        asm volatile("" ::: "memory"); // loads above cannot sink below this point
    };

    auto RED = [&](int base) {
        int v = lane >> 2, sub = lane & 3;
        const float4* rp4 = (const float4*)&red[v][0];
        float4 x0 = rp4[sub * 4 + 0];
        float4 x1 = rp4[sub * 4 + 1];
        float4 x2 = rp4[sub * 4 + 2];
        float4 x3 = rp4[sub * 4 + 3];
        float sA = (x0.x + x0.y) + (x0.z + x0.w);
        float sB = (x1.x + x1.y) + (x1.z + x1.w);
        float sC = (x2.x + x2.y) + (x2.z + x2.w);
        float sD = (x3.x + x3.y) + (x3.z + x3.w);
        float sm = (sA + sB) + (sC + sD);
        sm += __shfl_xor(sm, 1);
        sm += __shfl_xor(sm, 2);
        int tt = base + v;
        if (sub == 0 && tt < NTT) outp[(size_t)tt * NSS + s] = sm;
    };

    for (int tb = 0; tb < 368; tb += 16) {
        GROUP(tb, A);
        GROUP(tb + 8, B);
        RED(tb);
    }
#undef NVLD
}

__global__ __launch_bounds__(64) __attribute__((amdgpu_waves_per_eu(1, 2)))
void k_scan(
    const float* __restrict__ wsite, const float* __restrict__ rsite,
    const float* __restrict__ gaw,
    const float* __restrict__ ctp8, const float* __restrict__ ctpb,
    const float4* __restrict__ PTt, const unsigned* __restrict__ NVu,
    float* __restrict__ pQ, float* __restrict__ pC)
{
    __shared__ float4 ptlds[TPAD2];                // 6656 B
    __shared__ __align__(16) float red[16][68];    // 4352 B
    int lane = threadIdx.x;
    int b = blockIdx.x;
    // XCD-pairing: both roles of a site share b mod 8 (same XCD under round-robin)
    int lo = b & 7, q = b >> 3;
    int s = (q >> 1) * 8 + lo;
    int role = q & 1;
    if (s >= NSS) return;

    for (int t = lane; t < TPAD2; t += 64) ptlds[t] = PTt[(size_t)s * TPAD2 + t];

    const float* wrow = wsite + s * 896;
    if (role == 0)
        scan_body<0>(lane, s, wrow, rsite, gaw, ctp8, ctpb, NVu, ptlds, red, pQ);
    else
        scan_body<1>(lane, s, wrow, rsite, gaw, ctp8, ctpb, NVu, ptlds, red, pC);
}

// ---------------- K4: divide ----------------
__global__ __launch_bounds__(256) void k_final(const float* __restrict__ pQ,
                                               const float* __restrict__ pC,
                                               float* __restrict__ out)
{
    int i = blockIdx.x * 256 + threadIdx.x;
    if (i < NROWS) {
        float q = pQ[i];
        out[i] = q;
        out[NROWS + i] = pC[i] / q;
    }
}

extern "C" void kernel_launch(void* const* d_in, const int* in_sizes, int n_in,
                              void* d_out, int out_size, void* d_ws, size_t ws_size,
                              hipStream_t stream)
{
    const float* x      = (const float*)d_in[0];
    const float* xc     = (const float*)d_in[1];
    const float* fcR_w1 = (const float*)d_in[2];
    const float* fcR_b1 = (const float*)d_in[3];
    const float* fcR_w2 = (const float*)d_in[4];
    const float* fcR_b2 = (const float*)d_in[5];
    const float* fcW_w1 = (const float*)d_in[6];
    const float* fcW_b1 = (const float*)d_in[7];
    const float* fcW_w2 = (const float*)d_in[8];
    const float* fcW_b2 = (const float*)d_in[9];
    const float* fcT_w1 = (const float*)d_in[10];
    const float* fcT_b1 = (const float*)d_in[11];
    const float* fcT_w2 = (const float*)d_in[12];
    const float* fcT_b2 = (const float*)d_in[13];
    const float* fcCT_w = (const float*)d_in[14];
    const float* fcCT_b = (const float*)d_in[15];
    float* out = (float*)d_out;

    float* ws = (float*)d_ws;
    size_t o_w    = 0;                                     // 300*896
    size_t o_r    = o_w  + 300 * 896;                      // 300*1024
    size_t o_ga   = o_r  + 300 * 1024;                     // 300*128
    size_t o_PT   = o_ga + 300 * 128;                      // NSS*TPAD2 float4
    size_t o_NV   = o_PT + (size_t)TPAD2 * NSS * 4;        // NVROWS*NSS*128 u32
    size_t o_pQ   = o_NV + (size_t)NVROWS * NSS * 128;     // NROWS
    size_t o_pC   = o_pQ + (size_t)NROWS;                  // NROWS
    size_t o_w1bf = o_pC + (size_t)NROWS;
    size_t o_w2bf = o_w1bf + 8192;
    size_t o_ctp  = o_w2bf + 49152;                        // 300*128*8
    size_t o_ctpb = o_ctp + (size_t)300 * 128 * 8;         // 300*128

    float* wsite = ws + o_w;
    float* rsite = ws + o_r;
    float* gaw   = ws + o_ga;
    float4* PTt  = (float4*)(ws + o_PT);
    unsigned* NVu = (unsigned*)(ws + o_NV);
    float* pQ    = ws + o_pQ;
    float* pC    = ws + o_pC;
    unsigned short* w1s = (unsigned short*)(ws + o_w1bf);
    unsigned short* w2s = (unsigned short*)(ws + o_w2bf);
    float* ctp8  = ws + o_ctp;
    float* ctpb  = ws + o_ctpb;

    k_prep<<<56, 256, 0, stream>>>(fcT_w1, fcT_w2, w1s, w2s);
    k_site<<<dim3(30, 8), 256, 0, stream>>>(xc, fcW_w1, fcW_b1, fcW_w2, fcW_b2,
                                            fcR_w1, fcR_b1, fcR_w2, fcR_b2, wsite, rsite);
    k_softmax_ga<<<300, 128, 0, stream>>>(wsite, gaw);
    k_ct<<<300, 128, 0, stream>>>(xc, fcCT_w, fcCT_b, ctp8, ctpb);
    int nblk2 = (NROWS + 63) / 64;   // 1711
    k_fcT<<<nblk2, 512, 0, stream>>>(x, xc, w1s, fcT_b1, w2s, fcT_b2, PTt, NVu);
    // 300 sites x 2 roles, XCD-paired encoding; 608 blocks (8 guarded off)
    k_scan<<<608, 64, 0, stream>>>(wsite, rsite, gaw, ctp8, ctpb,
                                   PTt, NVu, pQ, pC);
    k_final<<<(NROWS + 255) / 256, 256, 0, stream>>>(pQ, pC, out);
}